// Round 3
// baseline (955.016 us; speedup 1.0000x reference)
//
#include <hip/hip_runtime.h>
#include <math.h>

namespace {

constexpr int kB = 512, kI = 1152, kD = 8, kJ = 10, kC = 16;
constexpr int TB = 2;                       // batches per block
constexpr int THREADS = 512;                // 8 waves
constexpr int ROWS = kI / (THREADS / 4);    // 9 i-rows per thread
constexpr float EPS = 1e-7f;

// Thread (g = t>>2, c4 = t&3) owns i-rows {g + 128*it} and channels {4*c4..4*c4+3}.
// x_hat stays in registers end-to-end; LDS is only tiny reduction scratch.
__launch_bounds__(THREADS, 4)   // cap VGPR at 128 -> 2 blocks/CU
__global__ void digitcaps_fused(const float* __restrict__ x,
                                const float* __restrict__ W,
                                float* __restrict__ out) {
  __shared__ float sredS[TB][8][kC];   // per-wave partial s (1 KB)
  __shared__ float sredZ[TB][8];
  __shared__ float sredM[TB][8];

  const int t    = threadIdx.x;
  const int lane = t & 63;
  const int wid  = t >> 6;
  const int c4   = t & 3;
  const int g    = t >> 2;

  const int bid = blockIdx.x;
  const int j   = bid >> 8;            // j-major: W[j] (590 KB) stays hot in XCD L2
  const int b0  = (bid & 255) * TB;

  float xh[TB][ROWS][4];               // register-resident x_hat fragments

  // ---------------- Phase 1: x_hat = einsum(x, W), no LDS, no barriers ------
  #pragma unroll
  for (int it = 0; it < ROWS; ++it) {
    const int i = it * 128 + g;
    const float* Wp = W + (size_t)(j * kI + i) * (kD * kC) + (c4 << 2);
    float xr[TB][kD];
    #pragma unroll
    for (int tb = 0; tb < TB; ++tb) {
      const float4* xp = reinterpret_cast<const float4*>(
          x + (size_t)((b0 + tb) * kI + i) * kD);
      const float4 v0 = xp[0], v1 = xp[1];
      xr[tb][0] = v0.x; xr[tb][1] = v0.y; xr[tb][2] = v0.z; xr[tb][3] = v0.w;
      xr[tb][4] = v1.x; xr[tb][5] = v1.y; xr[tb][6] = v1.z; xr[tb][7] = v1.w;
    }
    float a[TB][4] = {};
    #pragma unroll
    for (int d = 0; d < kD; ++d) {
      const float4 w = *reinterpret_cast<const float4*>(Wp + d * kC);
      #pragma unroll
      for (int tb = 0; tb < TB; ++tb) {
        a[tb][0] += xr[tb][d] * w.x;
        a[tb][1] += xr[tb][d] * w.y;
        a[tb][2] += xr[tb][d] * w.z;
        a[tb][3] += xr[tb][d] * w.w;
      }
    }
    #pragma unroll
    for (int tb = 0; tb < TB; ++tb)
      #pragma unroll
      for (int k = 0; k < 4; ++k) xh[tb][it][k] = a[tb][k];
  }

  // ---------------- Phase 2: 3 routing iterations, register math ------------
  float bl[TB][ROWS];                  // routing logits b_i (identical across c4 lanes)
  #pragma unroll
  for (int tb = 0; tb < TB; ++tb)
    #pragma unroll
    for (int r = 0; r < ROWS; ++r) bl[tb][r] = 0.f;

  #pragma unroll
  for (int itr = 0; itr < 3; ++itr) {
    // --- softmax max over i: local 9 -> g-butterfly -> cross-wave (LDS) ---
    float mx[TB];
    #pragma unroll
    for (int tb = 0; tb < TB; ++tb) {
      float mm = bl[tb][0];
      #pragma unroll
      for (int r = 1; r < ROWS; ++r) mm = fmaxf(mm, bl[tb][r]);
      #pragma unroll
      for (int off = 4; off < 64; off <<= 1)
        mm = fmaxf(mm, __shfl_xor(mm, off, 64));
      mx[tb] = mm;
    }
    if (lane == 0) {
      #pragma unroll
      for (int tb = 0; tb < TB; ++tb) sredM[tb][wid] = mx[tb];
    }
    __syncthreads();
    float m[TB];
    #pragma unroll
    for (int tb = 0; tb < TB; ++tb) {
      float mm = sredM[tb][0];
      #pragma unroll
      for (int w = 1; w < 8; ++w) mm = fmaxf(mm, sredM[tb][w]);
      m[tb] = mm;
    }

    // --- e_i, partial Z, partial s over own 4 channels ---
    float zp[TB], sp[TB][4];
    #pragma unroll
    for (int tb = 0; tb < TB; ++tb) {
      zp[tb] = 0.f;
      sp[tb][0] = sp[tb][1] = sp[tb][2] = sp[tb][3] = 0.f;
      #pragma unroll
      for (int r = 0; r < ROWS; ++r) {
        const float e = expf(bl[tb][r] - m[tb]);
        zp[tb]    += e;
        sp[tb][0] += e * xh[tb][r][0];
        sp[tb][1] += e * xh[tb][r][1];
        sp[tb][2] += e * xh[tb][r][2];
        sp[tb][3] += e * xh[tb][r][3];
      }
    }
    #pragma unroll
    for (int off = 4; off < 64; off <<= 1) {   // reduce over g within wave
      #pragma unroll
      for (int tb = 0; tb < TB; ++tb) {
        zp[tb]    += __shfl_xor(zp[tb], off, 64);
        sp[tb][0] += __shfl_xor(sp[tb][0], off, 64);
        sp[tb][1] += __shfl_xor(sp[tb][1], off, 64);
        sp[tb][2] += __shfl_xor(sp[tb][2], off, 64);
        sp[tb][3] += __shfl_xor(sp[tb][3], off, 64);
      }
    }
    if (lane < 4) {                            // lane l holds c4=l wave-partial
      #pragma unroll
      for (int tb = 0; tb < TB; ++tb) {
        float4 v4;
        v4.x = sp[tb][0]; v4.y = sp[tb][1]; v4.z = sp[tb][2]; v4.w = sp[tb][3];
        *reinterpret_cast<float4*>(&sredS[tb][wid][lane * 4]) = v4;
      }
    }
    if (lane == 0) {
      #pragma unroll
      for (int tb = 0; tb < TB; ++tb) sredZ[tb][wid] = zp[tb];
    }
    __syncthreads();

    // --- combine wave partials; squash (uniform per (tb)) ---
    float sv[TB][4], fac[TB];
    #pragma unroll
    for (int tb = 0; tb < TB; ++tb) {
      float Z = 0.f;
      #pragma unroll
      for (int w = 0; w < 8; ++w) Z += sredZ[tb][w];
      float s0 = 0.f, s1 = 0.f, s2 = 0.f, s3 = 0.f;
      #pragma unroll
      for (int w = 0; w < 8; ++w) {
        const float4 v4 = *reinterpret_cast<const float4*>(&sredS[tb][w][c4 * 4]);
        s0 += v4.x; s1 += v4.y; s2 += v4.z; s3 += v4.w;
      }
      const float invZ = 1.f / Z;
      sv[tb][0] = s0 * invZ; sv[tb][1] = s1 * invZ;
      sv[tb][2] = s2 * invZ; sv[tb][3] = s3 * invZ;
      float pq = sv[tb][0] * sv[tb][0] + sv[tb][1] * sv[tb][1]
               + sv[tb][2] * sv[tb][2] + sv[tb][3] * sv[tb][3];
      pq += __shfl_xor(pq, 1, 64);             // sum ssq across c4 groups
      pq += __shfl_xor(pq, 2, 64);
      const float nrm = sqrtf(pq);
      fac[tb] = pq / ((1.f + pq) * (nrm + EPS));
    }

    if (itr < 2) {
      // --- agreement: b_i += dot(v, x_hat[i,:]); partial over 4 ch + c4-butterfly
      #pragma unroll
      for (int tb = 0; tb < TB; ++tb) {
        const float vc0 = fac[tb] * sv[tb][0], vc1 = fac[tb] * sv[tb][1];
        const float vc2 = fac[tb] * sv[tb][2], vc3 = fac[tb] * sv[tb][3];
        #pragma unroll
        for (int r = 0; r < ROWS; ++r) {
          float dp = vc0 * xh[tb][r][0] + vc1 * xh[tb][r][1]
                   + vc2 * xh[tb][r][2] + vc3 * xh[tb][r][3];
          dp += __shfl_xor(dp, 1, 64);         // sum across c4 (same g)
          dp += __shfl_xor(dp, 2, 64);
          bl[tb][r] += dp;
        }
      }
    } else {
      // --- final write: thread t<4 writes its 4 channels as float4 ---
      if (t < 4) {
        #pragma unroll
        for (int tb = 0; tb < TB; ++tb) {
          float4 o;
          o.x = fac[tb] * sv[tb][0]; o.y = fac[tb] * sv[tb][1];
          o.z = fac[tb] * sv[tb][2]; o.w = fac[tb] * sv[tb][3];
          *reinterpret_cast<float4*>(out + ((size_t)(b0 + tb) * kJ + j) * kC + t * 4) = o;
        }
      }
    }
  }
}

}  // namespace

extern "C" void kernel_launch(void* const* d_in, const int* in_sizes, int n_in,
                              void* d_out, int out_size, void* d_ws, size_t ws_size,
                              hipStream_t stream) {
  (void)in_sizes; (void)n_in; (void)d_ws; (void)ws_size; (void)out_size;
  const float* x = reinterpret_cast<const float*>(d_in[0]);
  const float* W = reinterpret_cast<const float*>(d_in[1]);
  float* out = reinterpret_cast<float*>(d_out);
  const int grid = (kB / TB) * kJ;  // 2560 blocks, j-major
  digitcaps_fused<<<grid, THREADS, 0, stream>>>(x, W, out);
}

// Round 4
// 772.525 us; speedup vs baseline: 1.2362x; 1.2362x over previous
//
#include <hip/hip_runtime.h>
#include <math.h>

namespace {

constexpr int kB = 512, kI = 1152, kD = 8, kJ = 10, kC = 16;
constexpr int TB = 2;                       // batches per block
constexpr int THREADS = 512;                // 8 waves
constexpr int ROWS = kI / (THREADS / 4);    // 9 i-rows per thread
constexpr float EPS = 1e-7f;

// Thread (g = t>>2, c4 = t&3) owns i-rows {g + 128*it} and channels {4*c4..4*c4+3}.
// x_hat lives in registers end-to-end (72 floats/thread, statically indexed).
// NOTE: no waves-per-EU bound — round 3 showed __launch_bounds__(512,4) forces a
// 64-VGPR cap and spills xh to scratch (2.7 GB of HBM spill traffic). Unbounded,
// the allocator can take ~110-130 VGPRs -> still 2 blocks/CU, zero spill.
__launch_bounds__(THREADS)
__global__ void digitcaps_fused(const float* __restrict__ x,
                                const float* __restrict__ W,
                                float* __restrict__ out) {
  __shared__ float sredS[8][kC];       // per-wave partial s (512 B)
  __shared__ float sredZ[8];
  __shared__ float sredM[8];

  const int t    = threadIdx.x;
  const int lane = t & 63;
  const int wid  = t >> 6;
  const int c4   = t & 3;
  const int g    = t >> 2;

  const int bid = blockIdx.x;
  const int j   = bid >> 8;            // j-major: W[j] (590 KB) stays hot in XCD L2
  const int b0  = (bid & 255) * TB;

  float xh[TB][ROWS][4];               // register-resident x_hat fragments

  // ---------------- Phase 1: x_hat = einsum(x, W), no LDS, no barriers ------
  #pragma unroll
  for (int it = 0; it < ROWS; ++it) {
    const int i = it * 128 + g;
    const float* Wp = W + (size_t)(j * kI + i) * (kD * kC) + (c4 << 2);
    float xr[TB][kD];
    #pragma unroll
    for (int tb = 0; tb < TB; ++tb) {
      const float4* xp = reinterpret_cast<const float4*>(
          x + (size_t)((b0 + tb) * kI + i) * kD);
      const float4 v0 = xp[0], v1 = xp[1];
      xr[tb][0] = v0.x; xr[tb][1] = v0.y; xr[tb][2] = v0.z; xr[tb][3] = v0.w;
      xr[tb][4] = v1.x; xr[tb][5] = v1.y; xr[tb][6] = v1.z; xr[tb][7] = v1.w;
    }
    float a[TB][4] = {};
    #pragma unroll
    for (int d = 0; d < kD; ++d) {
      const float4 w = *reinterpret_cast<const float4*>(Wp + d * kC);
      #pragma unroll
      for (int tb = 0; tb < TB; ++tb) {
        a[tb][0] += xr[tb][d] * w.x;
        a[tb][1] += xr[tb][d] * w.y;
        a[tb][2] += xr[tb][d] * w.z;
        a[tb][3] += xr[tb][d] * w.w;
      }
    }
    #pragma unroll
    for (int tb = 0; tb < TB; ++tb)
      #pragma unroll
      for (int k = 0; k < 4; ++k) xh[tb][it][k] = a[tb][k];
  }

  // ---------------- Phase 2: routing, fully independent per batch -----------
  // tb loop OUTSIDE the routing loop: halves live temporaries vs round 3.
  #pragma unroll
  for (int tb = 0; tb < TB; ++tb) {
    float bl[ROWS];
    #pragma unroll
    for (int r = 0; r < ROWS; ++r) bl[r] = 0.f;

    #pragma unroll
    for (int itr = 0; itr < 3; ++itr) {
      // --- softmax max over i: local 9 -> g-butterfly -> cross-wave (LDS) ---
      float mm = bl[0];
      #pragma unroll
      for (int r = 1; r < ROWS; ++r) mm = fmaxf(mm, bl[r]);
      #pragma unroll
      for (int off = 4; off < 64; off <<= 1)
        mm = fmaxf(mm, __shfl_xor(mm, off, 64));
      if (lane == 0) sredM[wid] = mm;
      __syncthreads();                                   // barrier A
      float m = sredM[0];
      #pragma unroll
      for (int w = 1; w < 8; ++w) m = fmaxf(m, sredM[w]);

      // --- e_i, partial Z, partial s over own 4 channels ---
      float zp = 0.f, sp0 = 0.f, sp1 = 0.f, sp2 = 0.f, sp3 = 0.f;
      #pragma unroll
      for (int r = 0; r < ROWS; ++r) {
        const float e = expf(bl[r] - m);
        zp  += e;
        sp0 += e * xh[tb][r][0];
        sp1 += e * xh[tb][r][1];
        sp2 += e * xh[tb][r][2];
        sp3 += e * xh[tb][r][3];
      }
      #pragma unroll
      for (int off = 4; off < 64; off <<= 1) {           // reduce over g in-wave
        zp  += __shfl_xor(zp,  off, 64);
        sp0 += __shfl_xor(sp0, off, 64);
        sp1 += __shfl_xor(sp1, off, 64);
        sp2 += __shfl_xor(sp2, off, 64);
        sp3 += __shfl_xor(sp3, off, 64);
      }
      if (lane < 4) {                                    // lane l holds c4=l partial
        float4 v4; v4.x = sp0; v4.y = sp1; v4.z = sp2; v4.w = sp3;
        *reinterpret_cast<float4*>(&sredS[wid][lane * 4]) = v4;
      }
      if (lane == 0) sredZ[wid] = zp;
      __syncthreads();                                   // barrier B

      // --- combine wave partials; squash (uniform across block) ---
      float Z = 0.f;
      #pragma unroll
      for (int w = 0; w < 8; ++w) Z += sredZ[w];
      float s0 = 0.f, s1 = 0.f, s2 = 0.f, s3 = 0.f;
      #pragma unroll
      for (int w = 0; w < 8; ++w) {
        const float4 v4 = *reinterpret_cast<const float4*>(&sredS[w][c4 * 4]);
        s0 += v4.x; s1 += v4.y; s2 += v4.z; s3 += v4.w;
      }
      const float invZ = 1.f / Z;
      s0 *= invZ; s1 *= invZ; s2 *= invZ; s3 *= invZ;
      float pq = s0 * s0 + s1 * s1 + s2 * s2 + s3 * s3;
      pq += __shfl_xor(pq, 1, 64);                       // sum ssq across c4
      pq += __shfl_xor(pq, 2, 64);
      const float nrm = sqrtf(pq);
      const float fac = pq / ((1.f + pq) * (nrm + EPS));

      if (itr < 2) {
        // --- agreement: b_i += dot(v, x_hat[i,:]) ---
        const float vc0 = fac * s0, vc1 = fac * s1, vc2 = fac * s2, vc3 = fac * s3;
        #pragma unroll
        for (int r = 0; r < ROWS; ++r) {
          float dp = vc0 * xh[tb][r][0] + vc1 * xh[tb][r][1]
                   + vc2 * xh[tb][r][2] + vc3 * xh[tb][r][3];
          dp += __shfl_xor(dp, 1, 64);                   // sum across c4 (same g)
          dp += __shfl_xor(dp, 2, 64);
          bl[r] += dp;
        }
      } else {
        // --- final write: thread t<4 writes its 4 channels as float4 ---
        if (t < 4) {
          float4 o;
          o.x = fac * s0; o.y = fac * s1; o.z = fac * s2; o.w = fac * s3;
          *reinterpret_cast<float4*>(out + ((size_t)(b0 + tb) * kJ + j) * kC + t * 4) = o;
        }
      }
      // Barrier safety: sredM reads finish before barrier B; sredZ/sredS reads
      // finish before the NEXT barrier A. Two barriers per iteration suffice.
    }
  }
}

}  // namespace

extern "C" void kernel_launch(void* const* d_in, const int* in_sizes, int n_in,
                              void* d_out, int out_size, void* d_ws, size_t ws_size,
                              hipStream_t stream) {
  (void)in_sizes; (void)n_in; (void)d_ws; (void)ws_size; (void)out_size;
  const float* x = reinterpret_cast<const float*>(d_in[0]);
  const float* W = reinterpret_cast<const float*>(d_in[1]);
  float* out = reinterpret_cast<float*>(d_out);
  const int grid = (kB / TB) * kJ;  // 2560 blocks, j-major
  digitcaps_fused<<<grid, THREADS, 0, stream>>>(x, W, out);
}

// Round 5
// 658.066 us; speedup vs baseline: 1.4512x; 1.1739x over previous
//
#include <hip/hip_runtime.h>
#include <math.h>

namespace {

constexpr int kB = 512, kI = 1152, kD = 8, kJ = 10, kC = 16;
constexpr int THREADS = 512;                // 8 waves
constexpr int ROWS = kI / (THREADS / 4);    // 9 i-rows per thread
constexpr float EPS = 1e-7f;

// One (batch, j) pair per block. Thread (g = t>>2, c4 = t&3) owns i-rows
// {g + 128*it, it<9} and channels {4*c4..4*c4+3}. x_hat lives in registers
// (36 floats/thread, statically indexed).
//
// Register-budget lesson (rounds 3-4): TB=2 needs ~140 live VGPRs once the
// scheduler pipelines the W loads; any cap <=128 spills xh to scratch and the
// 2.1 GB scratch bounce IS the runtime (755 us at 2.8 TB/s). TB=1 needs ~85,
// fits the compiler's 128-reg occupancy target with margin -> zero spill,
// 2 blocks/CU for barrier overlap.
__launch_bounds__(THREADS)
__global__ void digitcaps_fused(const float* __restrict__ x,
                                const float* __restrict__ W,
                                float* __restrict__ out) {
  __shared__ float sredS[8][kC];       // per-wave partial s (512 B)
  __shared__ float sredZ[8];
  __shared__ float sredM[8];

  const int t    = threadIdx.x;
  const int lane = t & 63;
  const int wid  = t >> 6;
  const int c4   = t & 3;
  const int g    = t >> 2;

  const int bid = blockIdx.x;
  const int j   = bid >> 9;            // j-major: 512 consecutive blocks share W[j]
  const int b   = bid & 511;           // batch index

  float xh[ROWS][4];                   // register-resident x_hat fragments

  // ---------------- Phase 1: x_hat[b,j,i,c] = sum_d x[b,i,d]*W[j,i,d,c] -----
  #pragma unroll
  for (int it = 0; it < ROWS; ++it) {
    const int i = it * 128 + g;
    const float* Wp = W + (size_t)(j * kI + i) * (kD * kC) + (c4 << 2);
    const float4* xp = reinterpret_cast<const float4*>(
        x + (size_t)(b * kI + i) * kD);
    const float4 v0 = xp[0], v1 = xp[1];
    float xr[kD];
    xr[0] = v0.x; xr[1] = v0.y; xr[2] = v0.z; xr[3] = v0.w;
    xr[4] = v1.x; xr[5] = v1.y; xr[6] = v1.z; xr[7] = v1.w;
    float a0 = 0.f, a1 = 0.f, a2 = 0.f, a3 = 0.f;
    #pragma unroll
    for (int d = 0; d < kD; ++d) {
      const float4 w = *reinterpret_cast<const float4*>(Wp + d * kC);
      a0 += xr[d] * w.x;
      a1 += xr[d] * w.y;
      a2 += xr[d] * w.z;
      a3 += xr[d] * w.w;
    }
    xh[it][0] = a0; xh[it][1] = a1; xh[it][2] = a2; xh[it][3] = a3;
  }

  // ---------------- Phase 2: 3 routing iterations, register math ------------
  float bl[ROWS];
  #pragma unroll
  for (int r = 0; r < ROWS; ++r) bl[r] = 0.f;

  #pragma unroll
  for (int itr = 0; itr < 3; ++itr) {
    // --- softmax max over i: local 9 -> g-butterfly -> cross-wave (LDS) ---
    float mm = bl[0];
    #pragma unroll
    for (int r = 1; r < ROWS; ++r) mm = fmaxf(mm, bl[r]);
    #pragma unroll
    for (int off = 4; off < 64; off <<= 1)
      mm = fmaxf(mm, __shfl_xor(mm, off, 64));
    if (lane == 0) sredM[wid] = mm;
    __syncthreads();                                   // barrier A
    float m = sredM[0];
    #pragma unroll
    for (int w = 1; w < 8; ++w) m = fmaxf(m, sredM[w]);

    // --- e_i, partial Z, partial s over own 4 channels ---
    float zp = 0.f, sp0 = 0.f, sp1 = 0.f, sp2 = 0.f, sp3 = 0.f;
    #pragma unroll
    for (int r = 0; r < ROWS; ++r) {
      const float e = expf(bl[r] - m);
      zp  += e;
      sp0 += e * xh[r][0];
      sp1 += e * xh[r][1];
      sp2 += e * xh[r][2];
      sp3 += e * xh[r][3];
    }
    #pragma unroll
    for (int off = 4; off < 64; off <<= 1) {           // reduce over g in-wave
      zp  += __shfl_xor(zp,  off, 64);
      sp0 += __shfl_xor(sp0, off, 64);
      sp1 += __shfl_xor(sp1, off, 64);
      sp2 += __shfl_xor(sp2, off, 64);
      sp3 += __shfl_xor(sp3, off, 64);
    }
    if (lane < 4) {                                    // lane l holds c4=l partial
      float4 v4; v4.x = sp0; v4.y = sp1; v4.z = sp2; v4.w = sp3;
      *reinterpret_cast<float4*>(&sredS[wid][lane * 4]) = v4;
    }
    if (lane == 0) sredZ[wid] = zp;
    __syncthreads();                                   // barrier B

    // --- combine wave partials; squash (uniform across block) ---
    float Z = 0.f;
    #pragma unroll
    for (int w = 0; w < 8; ++w) Z += sredZ[w];
    float s0 = 0.f, s1 = 0.f, s2 = 0.f, s3 = 0.f;
    #pragma unroll
    for (int w = 0; w < 8; ++w) {
      const float4 v4 = *reinterpret_cast<const float4*>(&sredS[w][c4 * 4]);
      s0 += v4.x; s1 += v4.y; s2 += v4.z; s3 += v4.w;
    }
    const float invZ = 1.f / Z;
    s0 *= invZ; s1 *= invZ; s2 *= invZ; s3 *= invZ;
    float pq = s0 * s0 + s1 * s1 + s2 * s2 + s3 * s3;
    pq += __shfl_xor(pq, 1, 64);                       // sum ssq across c4
    pq += __shfl_xor(pq, 2, 64);
    const float nrm = sqrtf(pq);
    const float fac = pq / ((1.f + pq) * (nrm + EPS));

    if (itr < 2) {
      // --- agreement: b_i += dot(v, x_hat[i,:]) ---
      const float vc0 = fac * s0, vc1 = fac * s1, vc2 = fac * s2, vc3 = fac * s3;
      #pragma unroll
      for (int r = 0; r < ROWS; ++r) {
        float dp = vc0 * xh[r][0] + vc1 * xh[r][1]
                 + vc2 * xh[r][2] + vc3 * xh[r][3];
        dp += __shfl_xor(dp, 1, 64);                   // sum across c4 (same g)
        dp += __shfl_xor(dp, 2, 64);
        bl[r] += dp;
      }
    } else {
      // --- final write: thread t<4 writes its 4 channels as float4 ---
      if (t < 4) {
        float4 o;
        o.x = fac * s0; o.y = fac * s1; o.z = fac * s2; o.w = fac * s3;
        *reinterpret_cast<float4*>(out + ((size_t)b * kJ + j) * kC + t * 4) = o;
      }
    }
    // Barrier safety: sredM is written pre-A / read pre-B; next write is after
    // the next iteration's A. sredZ/sredS written pre-B / read pre-next-A.
  }
}

}  // namespace

extern "C" void kernel_launch(void* const* d_in, const int* in_sizes, int n_in,
                              void* d_out, int out_size, void* d_ws, size_t ws_size,
                              hipStream_t stream) {
  (void)in_sizes; (void)n_in; (void)d_ws; (void)ws_size; (void)out_size;
  const float* x = reinterpret_cast<const float*>(d_in[0]);
  const float* W = reinterpret_cast<const float*>(d_in[1]);
  float* out = reinterpret_cast<float*>(d_out);
  const int grid = kB * kJ;  // 5120 blocks, j-major
  digitcaps_fused<<<grid, THREADS, 0, stream>>>(x, W, out);
}